// Round 1
// baseline (2234.786 us; speedup 1.0000x reference)
//
#include <hip/hip_runtime.h>

// SimpleRNN: h_{t+1} = tanh(h_t @ H^T + x_t @ U + b); out = h_T @ A^T + c
// T=512 B=2048 IN=28 HID=198 OUT=10, all fp32.
//
// Design: persistent kernel, grid=256 blocks (1/CU), 8 batch rows per block,
// 256 threads (4 waves, 1/SIMD). Recurrence via mfma_f32_16x16x32_bf16 with
// split-bf16 (hi+lo) emulated-fp32: 3 MFMA passes (hi*Bhi + lo*Bhi + hi*Blo).
// H/U fragments (stationary over t) live in registers; h round-trips through
// LDS stored directly in A-fragment order ([kt][lane][8 bf16]) so reads are
// conflict-free ds_read_b128. Ping-pong A buffers -> 1 barrier per step.
// x[t+1] prefetched each step. xu + bias folded into MFMA C-init.

#define T_STEPS 512
#define BATCH   2048
#define IN_DIM  28
#define HID     198
#define OUT_DIM 10
#define BB      8    // batch rows per block
#define KT      7    // K tiles of 32 -> 224 >= 198
#define NTILES  13   // N tiles of 16 -> 208 >= 198

typedef __attribute__((ext_vector_type(8))) __bf16 bf16x8;
typedef __attribute__((ext_vector_type(4))) float  floatx4;

__device__ __forceinline__ floatx4 mfma16(bf16x8 a, bf16x8 b, floatx4 c) {
    return __builtin_amdgcn_mfma_f32_16x16x32_bf16(a, b, c, 0, 0, 0);
}

__device__ __forceinline__ float fast_tanh(float x) {
    float ax = __builtin_fabsf(x);
    float e  = __expf(-2.0f * ax);           // v_exp based, ~2ulp
    float y  = (1.0f - e) / (1.0f + e);
    return __builtin_copysignf(y, x);
}

__global__ void __launch_bounds__(256, 1)
rnn_kernel(const float* __restrict__ x, const float* __restrict__ H,
           const float* __restrict__ U, const float* __restrict__ A,
           const float* __restrict__ bvec, const float* __restrict__ cvec,
           float* __restrict__ out)
{
    // A-fragment ping-pong buffers, laid out exactly as lanes read them:
    // lds_Ahi[buf][kt][lane][idx] : lane reads 16B at [kt][lane][0..7] (b128, conflict-free)
    __shared__ __align__(16) __bf16 lds_Ahi[2][KT][64][8];
    __shared__ __align__(16) __bf16 lds_Alo[2][KT][64][8];
    __shared__ float lds_h[BB][200];   // fp32 h at final step, for output GEMM

    const int tid  = threadIdx.x;
    const int lane = tid & 63;
    const int wv   = tid >> 6;          // wave id 0..3
    const int m    = lane & 15;         // M/N index within a 16-wide tile
    const int quad = lane >> 4;         // 0..3
    const int b0   = blockIdx.x * BB;   // first batch row of this block

    // zero A-frag buffers (h0 = 0; also zeroes pad so MFMA pads multiply cleanly)
    {
        __bf16* p0 = &lds_Ahi[0][0][0][0];
        __bf16* p1 = &lds_Alo[0][0][0][0];
        for (int i = tid; i < 2*KT*64*8; i += 256) { p0[i] = (__bf16)0.0f; p1[i] = (__bf16)0.0f; }
    }

    const int cnt = (wv == 3) ? 4 : 3;  // N-tiles per wave: {0-2},{3-5},{6-8},{9-12}

    // ---- stationary fragments: H (hi+lo), U (hi+lo), bias -- loaded once ----
    bf16x8 Bhi[4][KT], Blo[4][KT], Uhi[4], Ulo[4];
    float  bias[4];
    #pragma unroll
    for (int q = 0; q < 4; ++q) {
        const int nt = (q < 3) ? (wv*3 + q) : 12;
        const int j  = nt*16 + m;                    // output column (hidden unit)
        bias[q] = (j < HID) ? bvec[j] : 0.0f;
        #pragma unroll
        for (int kt = 0; kt < KT; ++kt) {
            bf16x8 hi8, lo8;
            #pragma unroll
            for (int idx = 0; idx < 8; ++idx) {
                int k = kt*32 + quad*8 + idx;
                float v = (j < HID && k < HID) ? H[j*HID + k] : 0.0f;  // B[k][j] = H[j][k]
                __bf16 h = (__bf16)v;
                hi8[idx] = h;
                lo8[idx] = (__bf16)(v - (float)h);
            }
            Bhi[q][kt] = hi8; Blo[q][kt] = lo8;
        }
        bf16x8 uh, ul;
        #pragma unroll
        for (int idx = 0; idx < 8; ++idx) {
            int i = quad*8 + idx;
            float v = (j < HID && i < IN_DIM) ? U[i*HID + j] : 0.0f;   // B[i][j] = U[i][j]
            __bf16 h = (__bf16)v;
            uh[idx] = h;
            ul[idx] = (__bf16)(v - (float)h);
        }
        Uhi[q] = uh; Ulo[q] = ul;
    }

    // ---- x fragment staging (A-operand for the xu MFMA) ----
    // A[m][i]: m = batch row (lane&15, rows 8..15 are pad/junk -> discarded),
    // i = quad*8 + idx (i >= 28 multiplied by zeroed U frags).
    const int mb = (m < BB) ? m : (BB - 1);                 // clamp pad rows to a valid addr
    const float* xrow = x + (size_t)(b0 + mb) * IN_DIM + quad*8;
    const size_t tstride = (size_t)BATCH * IN_DIM;

    floatx4 zero4 = {0.0f, 0.0f, 0.0f, 0.0f};
    floatx4 f0 = *(const floatx4*)xrow;                      // t = 0
    floatx4 f1 = (quad < 3) ? *(const floatx4*)(xrow + 4) : zero4;

    bf16x8 axhi, axlo;
    {
        float xv[8] = {f0[0],f0[1],f0[2],f0[3], f1[0],f1[1],f1[2],f1[3]};
        #pragma unroll
        for (int i = 0; i < 8; ++i) {
            __bf16 h = (__bf16)xv[i];
            axhi[i] = h; axlo[i] = (__bf16)(xv[i] - (float)h);
        }
    }

    // ================= time loop =================
    #pragma unroll 1
    for (int t = 0; t < T_STEPS; ++t) {
        const int rb = t & 1;        // read buffer
        const int wb = rb ^ 1;       // write buffer

        __syncthreads();             // prev epilogue writes (into rb) visible

        // prefetch x[t+1] (in flight across whole step body; no barrier until next iter)
        const int tn = (t + 1 < T_STEPS) ? (t + 1) : t;
        const float* p = xrow + (size_t)tn * tstride;
        floatx4 nf0 = *(const floatx4*)p;
        floatx4 nf1 = (quad < 3) ? *(const floatx4*)(p + 4) : zero4;

        // C init with bias, then xu = x@U (split: 3 passes)
        floatx4 acc[4];
        #pragma unroll
        for (int q = 0; q < 4; ++q) acc[q] = (floatx4){bias[q], bias[q], bias[q], bias[q]};
        #pragma unroll
        for (int q = 0; q < 4; ++q) if (q < cnt) acc[q] = mfma16(axhi, Uhi[q], acc[q]);
        #pragma unroll
        for (int q = 0; q < 4; ++q) if (q < cnt) acc[q] = mfma16(axlo, Uhi[q], acc[q]);
        #pragma unroll
        for (int q = 0; q < 4; ++q) if (q < cnt) acc[q] = mfma16(axhi, Ulo[q], acc[q]);

        // recurrence: h @ H^T, split-bf16 3-pass
        #pragma unroll
        for (int kt = 0; kt < KT; ++kt) {
            bf16x8 ahi = *(const bf16x8*)&lds_Ahi[rb][kt][lane][0];
            bf16x8 alo = *(const bf16x8*)&lds_Alo[rb][kt][lane][0];
            #pragma unroll
            for (int q = 0; q < 4; ++q) if (q < cnt) acc[q] = mfma16(ahi, Bhi[q][kt], acc[q]);
            #pragma unroll
            for (int q = 0; q < 4; ++q) if (q < cnt) acc[q] = mfma16(alo, Bhi[q][kt], acc[q]);
            #pragma unroll
            for (int q = 0; q < 4; ++q) if (q < cnt) acc[q] = mfma16(ahi, Blo[q][kt], acc[q]);
        }

        // epilogue: tanh, split hi/lo, scatter into next A-frag layout
        // value (r=row, j=col) -> lds_A[wb][j>>5][ r | ((j&31)>>3)<<4 ][ j&7 ]
        const int rbase = quad * 4;
        #pragma unroll
        for (int q = 0; q < 4; ++q) if (q < cnt) {
            const int nt = (q < 3) ? (wv*3 + q) : 12;
            const int j  = nt*16 + m;
            if (j < HID && rbase < BB) {
                const int ktd  = j >> 5;
                const int koff = j & 31;
                const int ldd  = ((koff >> 3) << 4);
                const int idx  = koff & 7;
                #pragma unroll
                for (int reg = 0; reg < 4; ++reg) {
                    const int r = rbase + reg;
                    if (r < BB) {
                        float v  = fast_tanh(acc[q][reg]);
                        __bf16 h = (__bf16)v;
                        lds_Ahi[wb][ktd][r | ldd][idx] = h;
                        lds_Alo[wb][ktd][r | ldd][idx] = (__bf16)(v - (float)h);
                        if (t == T_STEPS - 1) lds_h[r][j] = v;
                    }
                }
            }
        }

        // stage next x fragment (loads drained here, ~1 step of latency hiding)
        {
            float xv[8] = {nf0[0],nf0[1],nf0[2],nf0[3], nf1[0],nf1[1],nf1[2],nf1[3]};
            #pragma unroll
            for (int i = 0; i < 8; ++i) {
                __bf16 h = (__bf16)xv[i];
                axhi[i] = h; axlo[i] = (__bf16)(xv[i] - (float)h);
            }
        }
    }

    __syncthreads();

    // ---- output: out[b][o] = sum_k h[b][k]*A[o][k] + c[o]  (fp32 scalar, tiny) ----
    if (tid < BB * OUT_DIM) {
        const int r = tid / OUT_DIM;
        const int o = tid % OUT_DIM;
        float s = cvec[o];
        for (int k = 0; k < HID; ++k) s += lds_h[r][k] * A[o*HID + k];
        out[(size_t)(b0 + r) * OUT_DIM + o] = s;
    }
}

extern "C" void kernel_launch(void* const* d_in, const int* in_sizes, int n_in,
                              void* d_out, int out_size, void* d_ws, size_t ws_size,
                              hipStream_t stream) {
    const float* x  = (const float*)d_in[0];
    const float* H  = (const float*)d_in[1];
    const float* U  = (const float*)d_in[2];
    const float* A  = (const float*)d_in[3];
    const float* b  = (const float*)d_in[4];
    const float* c  = (const float*)d_in[5];
    float* out = (float*)d_out;

    rnn_kernel<<<dim3(BATCH / BB), dim3(256), 0, stream>>>(x, H, U, A, b, c, out);
}

// Round 2
// 875.464 us; speedup vs baseline: 2.5527x; 2.5527x over previous
//
#include <hip/hip_runtime.h>

// SimpleRNN: h_{t+1} = tanh(h_t @ H^T + x_t @ U + b); out = h_T @ A^T + c
// T=512 B=2048 IN=28 HID=198 OUT=10, all fp32.
//
// R2 design: persistent kernel, grid=256 (1 block/CU), BB=8 batch rows/block,
// 512 threads = 8 waves = 2 waves/SIMD (cross-wave latency hiding).
// 16 uniform N-tiles (2/wave, tiles >=13 are zero-padded phantoms).
// mfma_f32_16x16x32_bf16 with split-bf16 (hi+lo) emulated fp32:
//   acc = ahi*Bhi + alo*Bhi + ahi*Blo   (error ~2^-17 per product)
// H/U fragments stationary in registers (~190 VGPR, fits 2 waves/SIMD).
// h round-trips LDS in DEDUP A-frag layout: 32 unique 16B rows per kt
// (lanes m and m+8 broadcast-read the same address -> half LDS traffic).
// Accumulators split by kt parity -> dependent MFMA chains ~12 deep, 4/wave.
// tanh via v_exp_f32 + v_rcp_f32 (no IEEE div sequence).
// One __syncthreads per step; x[t+1] prefetched across the step body.

#define T_STEPS 512
#define BATCH   2048
#define IN_DIM  28
#define HID     198
#define OUT_DIM 10
#define BB      8    // batch rows per block
#define KT      7    // K tiles of 32 -> 224 >= 198
#define QT      2    // N-tiles per wave (8 waves x 2 = 16 tiles, 13 real)

typedef __attribute__((ext_vector_type(8))) __bf16 bf16x8;
typedef __attribute__((ext_vector_type(4))) float  floatx4;

__device__ __forceinline__ floatx4 mfma16(bf16x8 a, bf16x8 b, floatx4 c) {
    return __builtin_amdgcn_mfma_f32_16x16x32_bf16(a, b, c, 0, 0, 0);
}

// tanh(x) = sign(x) * (1 - 2e/(1+e)), e = exp(-2|x|) = 2^(-2*log2e*|x|)
__device__ __forceinline__ float fast_tanh(float x) {
    float ax = __builtin_fabsf(x);
    float e  = __builtin_amdgcn_exp2f(ax * -2.885390081777927f);
    float r  = __builtin_amdgcn_rcpf(1.0f + e);
    float y  = __builtin_fmaf(-(e + e), r, 1.0f);
    return __builtin_copysignf(y, x);
}

__global__ void __launch_bounds__(512, 2)
rnn_kernel(const float* __restrict__ x, const float* __restrict__ H,
           const float* __restrict__ U, const float* __restrict__ A,
           const float* __restrict__ bvec, const float* __restrict__ cvec,
           float* __restrict__ out)
{
    // Dedup A-frag ping-pong buffers: [buf][kt][qk*8 + row][idx]
    // lane (m,quad) reads 16B at [kt][quad*8 + (m&7)][0..7] (b128, broadcast for m>=8)
    __shared__ __align__(16) __bf16 lds_Ahi[2][KT][32][8];
    __shared__ __align__(16) __bf16 lds_Alo[2][KT][32][8];
    __shared__ float lds_h[BB][204];   // fp32 h at final step, for output GEMM

    const int tid  = threadIdx.x;
    const int lane = tid & 63;
    const int wv   = tid >> 6;          // wave id 0..7
    const int m    = lane & 15;         // M/N index within 16-wide tile
    const int quad = lane >> 4;         // 0..3
    const int r8   = lane & 7;          // dedup row index
    const int b0   = blockIdx.x * BB;

    // zero A-frag buffers (h0 = 0; zeros also cover phantom/pad regions)
    {
        __bf16* p0 = &lds_Ahi[0][0][0][0];
        __bf16* p1 = &lds_Alo[0][0][0][0];
        for (int i = tid; i < 2*KT*32*8; i += 512) { p0[i] = (__bf16)0.0f; p1[i] = (__bf16)0.0f; }
    }

    // ---- stationary fragments: H (hi+lo), U (hi+lo), bias ----
    bf16x8 Bhi[QT][KT], Blo[QT][KT], Uhi[QT], Ulo[QT];
    float  bias[QT];
    #pragma unroll
    for (int q = 0; q < QT; ++q) {
        const int j = (wv*QT + q)*16 + m;            // output column 0..255 (>=198 phantom)
        bias[q] = (j < HID) ? bvec[j] : 0.0f;
        #pragma unroll
        for (int kt = 0; kt < KT; ++kt) {
            bf16x8 hi8, lo8;
            #pragma unroll
            for (int idx = 0; idx < 8; ++idx) {
                int k = kt*32 + quad*8 + idx;
                float v = (j < HID && k < HID) ? H[j*HID + k] : 0.0f;  // B[k][j] = H[j][k]
                __bf16 h = (__bf16)v;
                hi8[idx] = h;
                lo8[idx] = (__bf16)(v - (float)h);
            }
            Bhi[q][kt] = hi8; Blo[q][kt] = lo8;
        }
        bf16x8 uh, ul;
        #pragma unroll
        for (int idx = 0; idx < 8; ++idx) {
            int i = quad*8 + idx;
            float v = (j < HID && i < IN_DIM) ? U[i*HID + j] : 0.0f;   // B[i][j] = U[i][j]
            __bf16 h = (__bf16)v;
            uh[idx] = h;
            ul[idx] = (__bf16)(v - (float)h);
        }
        Uhi[q] = uh; Ulo[q] = ul;
    }

    // ---- x fragment staging (A-operand rows 8-15 duplicate rows 0-7) ----
    const float* xrow = x + (size_t)(b0 + r8) * IN_DIM + quad*8;
    const size_t tstride = (size_t)BATCH * IN_DIM;

    floatx4 zero4 = {0.0f, 0.0f, 0.0f, 0.0f};
    floatx4 f0 = *(const floatx4*)xrow;                      // t = 0
    floatx4 f1 = (quad < 3) ? *(const floatx4*)(xrow + 4) : zero4;

    bf16x8 axhi, axlo;
    {
        float xv[8] = {f0[0],f0[1],f0[2],f0[3], f1[0],f1[1],f1[2],f1[3]};
        #pragma unroll
        for (int i = 0; i < 8; ++i) {
            __bf16 h = (__bf16)xv[i];
            axhi[i] = h; axlo[i] = (__bf16)(xv[i] - (float)h);
        }
    }

    // ================= time loop =================
    #pragma unroll 1
    for (int t = 0; t < T_STEPS; ++t) {
        const int rb = t & 1;        // read buffer
        const int wb = rb ^ 1;       // write buffer

        __syncthreads();             // prev epilogue writes (into rb) visible

        // prefetch x[t+1] (in flight across step body)
        const int tn = (t + 1 < T_STEPS) ? (t + 1) : t;
        const float* p = xrow + (size_t)tn * tstride;
        floatx4 nf0 = *(const floatx4*)p;
        floatx4 nf1 = (quad < 3) ? *(const floatx4*)(p + 4) : zero4;

        // two accumulator chains per tile (kt-parity split) -> 4 indep chains/wave
        floatx4 acc[QT][2];
        #pragma unroll
        for (int q = 0; q < QT; ++q) {
            acc[q][0] = zero4; acc[q][1] = zero4;
        }
        // xu = x@U (3 split passes), distributed across the two chains
        #pragma unroll
        for (int q = 0; q < QT; ++q) acc[q][0] = mfma16(axhi, Uhi[q], acc[q][0]);
        #pragma unroll
        for (int q = 0; q < QT; ++q) acc[q][1] = mfma16(axlo, Uhi[q], acc[q][1]);
        #pragma unroll
        for (int q = 0; q < QT; ++q) acc[q][1] = mfma16(axhi, Ulo[q], acc[q][1]);

        // recurrence: h @ H^T, split-bf16 3-pass, dedup A-frag reads
        #pragma unroll
        for (int kt = 0; kt < KT; ++kt) {
            const int s = kt & 1;
            bf16x8 ahi = *(const bf16x8*)&lds_Ahi[rb][kt][quad*8 + r8][0];
            bf16x8 alo = *(const bf16x8*)&lds_Alo[rb][kt][quad*8 + r8][0];
            #pragma unroll
            for (int q = 0; q < QT; ++q) acc[q][s] = mfma16(ahi, Bhi[q][kt], acc[q][s]);
            #pragma unroll
            for (int q = 0; q < QT; ++q) acc[q][s] = mfma16(alo, Bhi[q][kt], acc[q][s]);
            #pragma unroll
            for (int q = 0; q < QT; ++q) acc[q][s] = mfma16(ahi, Blo[q][kt], acc[q][s]);
        }

        // epilogue: combine chains + bias, tanh, split hi/lo, scatter to wb
        const int rbase = quad * 4;        // quads 0,1 own the 8 real C rows
        #pragma unroll
        for (int q = 0; q < QT; ++q) {
            const int j = (wv*QT + q)*16 + m;
            if (j < HID && rbase < BB) {
                const int ktd = j >> 5;
                const int qk  = (j >> 3) & 3;
                const int idx = j & 7;
                #pragma unroll
                for (int reg = 0; reg < 4; ++reg) {
                    const int r = rbase + reg;   // 0..7
                    float v  = fast_tanh(acc[q][0][reg] + acc[q][1][reg] + bias[q]);
                    __bf16 h = (__bf16)v;
                    lds_Ahi[wb][ktd][qk*8 + r][idx] = h;
                    lds_Alo[wb][ktd][qk*8 + r][idx] = (__bf16)(v - (float)h);
                    if (t == T_STEPS - 1) lds_h[r][j] = v;
                }
            }
        }

        // stage next x fragment
        {
            float xv[8] = {nf0[0],nf0[1],nf0[2],nf0[3], nf1[0],nf1[1],nf1[2],nf1[3]};
            #pragma unroll
            for (int i = 0; i < 8; ++i) {
                __bf16 h = (__bf16)xv[i];
                axhi[i] = h; axlo[i] = (__bf16)(xv[i] - (float)h);
            }
        }
    }

    __syncthreads();

    // ---- output: out[b][o] = sum_k h[b][k]*A[o][k] + c[o] (tiny, scalar) ----
    if (tid < BB * OUT_DIM) {
        const int r = tid / OUT_DIM;
        const int o = tid % OUT_DIM;
        float s = cvec[o];
        for (int k = 0; k < HID; ++k) s += lds_h[r][k] * A[o*HID + k];
        out[(size_t)(b0 + r) * OUT_DIM + o] = s;
    }
}

extern "C" void kernel_launch(void* const* d_in, const int* in_sizes, int n_in,
                              void* d_out, int out_size, void* d_ws, size_t ws_size,
                              hipStream_t stream) {
    const float* x  = (const float*)d_in[0];
    const float* H  = (const float*)d_in[1];
    const float* U  = (const float*)d_in[2];
    const float* A  = (const float*)d_in[3];
    const float* b  = (const float*)d_in[4];
    const float* c  = (const float*)d_in[5];
    float* out = (float*)d_out;

    rnn_kernel<<<dim3(BATCH / BB), dim3(512), 0, stream>>>(x, H, U, A, b, c, out);
}

// Round 3
// 831.426 us; speedup vs baseline: 2.6879x; 1.0530x over previous
//
#include <hip/hip_runtime.h>

// SimpleRNN: h_{t+1} = tanh(h_t @ H^T + x_t @ U + b); out = h_T @ A^T + c
// T=512 B=2048 IN=28 HID=198 OUT=10, all fp32.
//
// R3 design: persistent kernel, grid=256 (1 block/CU), BB=8 batch rows/block,
// 512 threads = 8 waves = 2 waves/SIMD. 16 N-tiles (2/wave, >=13 phantom).
//
// KEY TRICK (new): A-fragment rows 0-7 carry h_hi (bf16), rows 8-15 carry
// h_lo (bf16 residual). Two MFMA passes per tile:
//   pass1: A_pk @ Bhi -> C[0..7]=hi*Bhi, C[8..15]=lo*Bhi
//   pass2: A_pk @ Blo -> C[0..7]=hi*Blo, C[8..15]=lo*Blo
// Epilogue: C[r] + C[r+8] via __shfl(lane^32) gives the EXACT
// (hi+lo)*(Bhi+Blo) product. 16 MFMAs/tile (was 24), 7 LDS A-reads/wave
// (was 14). Same trick for x@U (x_hi rows 0-7, x_lo rows 8-15).
// One __syncthreads per step; x[t+1] prefetched across the step body.

#define T_STEPS 512
#define BATCH   2048
#define IN_DIM  28
#define HID     198
#define OUT_DIM 10
#define BB      8    // batch rows per block
#define KT      7    // K tiles of 32 -> 224 >= 198
#define QT      2    // N-tiles per wave (8 waves x 2 = 16 tiles, 13 real)

typedef __attribute__((ext_vector_type(8))) __bf16 bf16x8;
typedef __attribute__((ext_vector_type(4))) float  floatx4;

__device__ __forceinline__ floatx4 mfma16(bf16x8 a, bf16x8 b, floatx4 c) {
    return __builtin_amdgcn_mfma_f32_16x16x32_bf16(a, b, c, 0, 0, 0);
}

// tanh(x) = sign(x) * (1 - 2e/(1+e)), e = exp(-2|x|)
__device__ __forceinline__ float fast_tanh(float x) {
    float ax = __builtin_fabsf(x);
    float e  = __builtin_amdgcn_exp2f(ax * -2.885390081777927f);
    float r  = __builtin_amdgcn_rcpf(1.0f + e);
    float y  = __builtin_fmaf(-(e + e), r, 1.0f);
    return __builtin_copysignf(y, x);
}

__global__ void __launch_bounds__(512, 2)
rnn_kernel(const float* __restrict__ x, const float* __restrict__ H,
           const float* __restrict__ U, const float* __restrict__ A,
           const float* __restrict__ bvec, const float* __restrict__ cvec,
           float* __restrict__ out)
{
    // Packed A-frag ping-pong: [buf][kt][lane][idx], lane = quad*16 + m.
    // Lane's 16B row = A[m][kt*32 + quad*8 .. +7]; rows m<8 hold h_hi of
    // batch row m, rows m>=8 hold h_lo of batch row m-8.
    __shared__ __align__(16) __bf16 lds_A[2][KT][64][8];
    __shared__ float lds_h[BB][204];   // fp32 h at final step, for output GEMM

    const int tid  = threadIdx.x;
    const int lane = tid & 63;
    const int wv   = tid >> 6;          // wave id 0..7
    const int m    = lane & 15;         // A-row / C-col index within tile
    const int quad = lane >> 4;         // 0..3 (K-chunk for A/B, row-group for C)
    const int b0   = blockIdx.x * BB;

    // zero A-frag buffers (h0 = 0; zeros persist in phantom j/k regions)
    {
        __bf16* p0 = &lds_A[0][0][0][0];
        for (int i = tid; i < 2*KT*64*8; i += 512) p0[i] = (__bf16)0.0f;
    }

    // ---- stationary fragments: H (hi+lo), U (hi+lo), bias ----
    bf16x8 Bhi[QT][KT], Blo[QT][KT], Uhi[QT], Ulo[QT];
    float  bias_eff[QT];
    #pragma unroll
    for (int q = 0; q < QT; ++q) {
        const int j = (wv*QT + q)*16 + m;            // output column (>=198 phantom)
        // bias lands in C rows 0-7 only (quads 0,1); rows 8-15 carry lo-partials
        bias_eff[q] = (j < HID && quad < 2) ? bvec[j] : 0.0f;
        #pragma unroll
        for (int kt = 0; kt < KT; ++kt) {
            bf16x8 hi8, lo8;
            #pragma unroll
            for (int idx = 0; idx < 8; ++idx) {
                int k = kt*32 + quad*8 + idx;
                float v = (j < HID && k < HID) ? H[j*HID + k] : 0.0f;  // B[k][j] = H[j][k]
                __bf16 h = (__bf16)v;
                hi8[idx] = h;
                lo8[idx] = (__bf16)(v - (float)h);
            }
            Bhi[q][kt] = hi8; Blo[q][kt] = lo8;
        }
        bf16x8 uh, ul;
        #pragma unroll
        for (int idx = 0; idx < 8; ++idx) {
            int i = quad*8 + idx;
            float v = (j < HID && i < IN_DIM) ? U[i*HID + j] : 0.0f;   // B[i][j] = U[i][j]
            __bf16 h = (__bf16)v;
            uh[idx] = h;
            ul[idx] = (__bf16)(v - (float)h);
        }
        Uhi[q] = uh; Ulo[q] = ul;
    }

    // ---- x fragment staging: rows m<8 get x_hi, rows m>=8 get x_lo ----
    const int r8    = m & 7;            // batch row this lane's A-row maps to
    const bool isLo = (m >= 8);
    const float* xrow = x + (size_t)(b0 + r8) * IN_DIM + quad*8;
    const size_t tstride = (size_t)BATCH * IN_DIM;

    floatx4 zero4 = {0.0f, 0.0f, 0.0f, 0.0f};
    floatx4 f0 = *(const floatx4*)xrow;                      // t = 0
    floatx4 f1 = (quad < 3) ? *(const floatx4*)(xrow + 4) : zero4;

    bf16x8 ax;
    {
        float xv[8] = {f0[0],f0[1],f0[2],f0[3], f1[0],f1[1],f1[2],f1[3]};
        #pragma unroll
        for (int i = 0; i < 8; ++i) {
            __bf16 h = (__bf16)xv[i];
            ax[i] = isLo ? (__bf16)(xv[i] - (float)h) : h;
        }
    }

    // ================= time loop =================
    #pragma unroll 1
    for (int t = 0; t < T_STEPS; ++t) {
        const int rb = t & 1;        // read buffer
        const int wb = rb ^ 1;       // write buffer

        __syncthreads();             // prev epilogue writes (into rb) visible

        // prefetch x[t+1] (in flight across step body)
        const int tn = (t + 1 < T_STEPS) ? (t + 1) : t;
        const float* p = xrow + (size_t)tn * tstride;
        floatx4 nf0 = *(const floatx4*)p;
        floatx4 nf1 = (quad < 3) ? *(const floatx4*)(p + 4) : zero4;

        // two accumulator chains per tile: acc1 (Bhi pass), acc2 (Blo pass)
        floatx4 acc1[QT], acc2[QT];
        #pragma unroll
        for (int q = 0; q < QT; ++q) {
            acc1[q] = (floatx4){bias_eff[q], bias_eff[q], bias_eff[q], bias_eff[q]};
            acc2[q] = zero4;
        }
        // xu = x@U (packed hi/lo rows): 2 passes
        #pragma unroll
        for (int q = 0; q < QT; ++q) acc1[q] = mfma16(ax, Uhi[q], acc1[q]);
        #pragma unroll
        for (int q = 0; q < QT; ++q) acc2[q] = mfma16(ax, Ulo[q], acc2[q]);

        // recurrence: 1 ds_read + 4 MFMAs per kt
        #pragma unroll
        for (int kt = 0; kt < KT; ++kt) {
            bf16x8 a = *(const bf16x8*)&lds_A[rb][kt][lane][0];
            #pragma unroll
            for (int q = 0; q < QT; ++q) acc1[q] = mfma16(a, Bhi[q][kt], acc1[q]);
            #pragma unroll
            for (int q = 0; q < QT; ++q) acc2[q] = mfma16(a, Blo[q][kt], acc2[q]);
        }

        // epilogue: fold hi/lo row-halves, tanh, split hi/lo, scatter to wb.
        // C rows r (quads 0,1) and r+8 (quads 2,3) sum via lane^32 shuffle.
        #pragma unroll
        for (int q = 0; q < QT; ++q) {
            const int j = (wv*QT + q)*16 + m;
            float s[4], pr[4];
            #pragma unroll
            for (int reg = 0; reg < 4; ++reg) {
                s[reg]  = acc1[q][reg] + acc2[q][reg];
                pr[reg] = __shfl(s[reg], lane ^ 32, 64);   // all lanes participate
            }
            if (quad < 2 && j < HID) {
                const int ktd = j >> 5;
                const int qt_ = (j & 31) >> 3;
                const int idx = j & 7;
                #pragma unroll
                for (int reg = 0; reg < 4; ++reg) {
                    const int r = quad*4 + reg;            // 0..7
                    float v  = fast_tanh(s[reg] + pr[reg]);
                    __bf16 h = (__bf16)v;
                    lds_A[wb][ktd][qt_*16 + r][idx]     = h;                       // hi row
                    lds_A[wb][ktd][qt_*16 + r + 8][idx] = (__bf16)(v - (float)h);  // lo row
                    if (t == T_STEPS - 1) lds_h[r][j] = v;
                }
            }
        }

        // stage next x fragment
        {
            float xv[8] = {nf0[0],nf0[1],nf0[2],nf0[3], nf1[0],nf1[1],nf1[2],nf1[3]};
            #pragma unroll
            for (int i = 0; i < 8; ++i) {
                __bf16 h = (__bf16)xv[i];
                ax[i] = isLo ? (__bf16)(xv[i] - (float)h) : h;
            }
        }
    }

    __syncthreads();

    // ---- output: out[b][o] = sum_k h[b][k]*A[o][k] + c[o] (tiny, scalar) ----
    if (tid < BB * OUT_DIM) {
        const int r = tid / OUT_DIM;
        const int o = tid % OUT_DIM;
        float s = cvec[o];
        for (int k = 0; k < HID; ++k) s += lds_h[r][k] * A[o*HID + k];
        out[(size_t)(b0 + r) * OUT_DIM + o] = s;
    }
}

extern "C" void kernel_launch(void* const* d_in, const int* in_sizes, int n_in,
                              void* d_out, int out_size, void* d_ws, size_t ws_size,
                              hipStream_t stream) {
    const float* x  = (const float*)d_in[0];
    const float* H  = (const float*)d_in[1];
    const float* U  = (const float*)d_in[2];
    const float* A  = (const float*)d_in[3];
    const float* b  = (const float*)d_in[4];
    const float* c  = (const float*)d_in[5];
    float* out = (float*)d_out;

    rnn_kernel<<<dim3(BATCH / BB), dim3(512), 0, stream>>>(x, H, U, A, b, c, out);
}

// Round 4
// 623.980 us; speedup vs baseline: 3.5815x; 1.3325x over previous
//
#include <hip/hip_runtime.h>

// SimpleRNN: h_{t+1} = tanh(h_t @ H^T + x_t @ U + b); out = h_T @ A^T + c
// T=512 B=2048 IN=28 HID=198 OUT=10, all fp32.
//
// R4: persistent kernel, grid=256 (1 block/CU), BB=8 batch rows/block,
// 1024 threads = 16 waves = 4 waves/SIMD (phase overlap across waves).
// Waves 0-12: compute (1 N-tile of 16 cols each, 13x16=208 >= 198).
// Wave 15: x-stager (packs x[t+1] hi/lo A-frag into LDS slot kt=7).
// Waves 13,14: barrier-only.
//
// hi/lo-packed M (from R3): A rows 0-7 = h_hi, rows 8-15 = h_lo; 2 MFMA
// passes (Bhi, Blo) then fold C[r]+C[r+8] via shfl(lane^32) -> exact
// (hi+lo)*(Bhi+Blo). x@U folded into the same loop: slot kt=7 holds the
// packed x fragment, B[7] = U -> uniform 8-iter loop, 16 MFMAs/wave/step.
// All-lane epilogue: quads 0,1 write hi bf16; quads 2,3 write lo bf16.
// One __syncthreads per step.

#define T_STEPS 512
#define BATCH   2048
#define IN_DIM  28
#define HID     198
#define OUT_DIM 10
#define BB      8    // batch rows per block
#define KT      8    // 7 H k-tiles (224 >= 198) + 1 U/x slot
#define NCW     13   // compute waves / N-tiles

typedef __attribute__((ext_vector_type(8))) __bf16 bf16x8;
typedef __attribute__((ext_vector_type(4))) float  floatx4;

__device__ __forceinline__ floatx4 mfma16(bf16x8 a, bf16x8 b, floatx4 c) {
    return __builtin_amdgcn_mfma_f32_16x16x32_bf16(a, b, c, 0, 0, 0);
}

// tanh(x) = sign(x) * (1 - 2e/(1+e)), e = exp(-2|x|)
__device__ __forceinline__ float fast_tanh(float x) {
    float ax = __builtin_fabsf(x);
    float e  = __builtin_amdgcn_exp2f(ax * -2.885390081777927f);
    float r  = __builtin_amdgcn_rcpf(1.0f + e);
    float y  = __builtin_fmaf(-(e + e), r, 1.0f);
    return __builtin_copysignf(y, x);
}

__global__ void __launch_bounds__(1024, 4)
rnn_kernel(const float* __restrict__ x, const float* __restrict__ H,
           const float* __restrict__ U, const float* __restrict__ A,
           const float* __restrict__ bvec, const float* __restrict__ cvec,
           float* __restrict__ out)
{
    // A-frag ping-pong: [buf][kt][lane][idx]; lane = qt*16 + arow,
    // arow 0-7 = h_hi(batch row arow), 8-15 = h_lo(batch row arow-8).
    // Slot kt=7 holds the x fragment (written by the stager wave).
    __shared__ __align__(16) __bf16 lds_A[2][KT][64][8];   // 16 KB
    __shared__ float lds_h[BB][204];                        // final h, fp32

    const int tid  = threadIdx.x;
    const int lane = tid & 63;
    const int wv   = tid >> 6;          // wave id 0..15
    const int m    = lane & 15;         // A-row / C-col index within tile
    const int quad = lane >> 4;         // 0..3
    const int b0   = blockIdx.x * BB;

    // zero-init H-slots (kt 0..6) of both buffers: h0 = 0, phantom K rows
    // stay 0 forever (epilogue never writes k >= 198).
    {
        __bf16* p0 = &lds_A[0][0][0][0];
        __bf16* p1 = &lds_A[1][0][0][0];
        for (int i = tid; i < 7*64*8; i += 1024) { p0[i] = (__bf16)0.0f; p1[i] = (__bf16)0.0f; }
    }

    const int r8    = m & 7;
    const bool isLo = (m >= 8);

    // ---- compute-wave setup: stationary B fragments + epilogue indices ----
    bf16x8 Bhi[KT], Blo[KT];
    float  bias_eff = 0.0f;
    int    jcol = 0, e_ktd = 0, e_rowb = 0, e_idx = 0;
    bool   e_wr = false;
    if (wv < NCW) {
        jcol = wv*16 + m;                               // output column (>=198 phantom)
        bias_eff = (jcol < HID && quad < 2) ? bvec[jcol] : 0.0f;
        #pragma unroll
        for (int kt = 0; kt < 7; ++kt) {
            bf16x8 hi8, lo8;
            #pragma unroll
            for (int idx = 0; idx < 8; ++idx) {
                int k = kt*32 + quad*8 + idx;
                float v = (jcol < HID && k < HID) ? H[jcol*HID + k] : 0.0f;  // B[k][j]=H[j][k]
                __bf16 h = (__bf16)v;
                hi8[idx] = h;
                lo8[idx] = (__bf16)(v - (float)h);
            }
            Bhi[kt] = hi8; Blo[kt] = lo8;
        }
        {   // slot 7: U
            bf16x8 uh, ul;
            #pragma unroll
            for (int idx = 0; idx < 8; ++idx) {
                int i = quad*8 + idx;
                float v = (jcol < HID && i < IN_DIM) ? U[i*HID + jcol] : 0.0f;
                __bf16 h = (__bf16)v;
                uh[idx] = h;
                ul[idx] = (__bf16)(v - (float)h);
            }
            Bhi[7] = uh; Blo[7] = ul;
        }
        e_ktd  = jcol >> 5;
        e_rowb = ((jcol & 31) >> 3)*16 + quad*4;  // + reg gives the A-row slot
        e_idx  = jcol & 7;
        e_wr   = (jcol < HID);
    }

    // ---- stager-wave setup: pack x[0] into slot 7 of buffer 0 ----
    const float* xrow = x + (size_t)(b0 + r8) * IN_DIM + quad*8;
    const size_t tstride = (size_t)BATCH * IN_DIM;
    floatx4 zero4 = {0.0f, 0.0f, 0.0f, 0.0f};
    if (wv == 15) {
        floatx4 f0 = *(const floatx4*)xrow;
        floatx4 f1 = (quad < 3) ? *(const floatx4*)(xrow + 4) : zero4;
        float xv[8] = {f0[0],f0[1],f0[2],f0[3], f1[0],f1[1],f1[2],f1[3]};
        bf16x8 ax;
        #pragma unroll
        for (int i = 0; i < 8; ++i) {
            __bf16 h = (__bf16)xv[i];
            ax[i] = isLo ? (__bf16)(xv[i] - (float)h) : h;
        }
        *(bf16x8*)&lds_A[0][7][lane][0] = ax;
    }

    // ================= time loop =================
    #pragma unroll 1
    for (int t = 0; t < T_STEPS; ++t) {
        const int rb = t & 1;
        const int wb = rb ^ 1;

        __syncthreads();   // all prior writes into rb visible; wb free to write

        if (wv < NCW) {
            floatx4 acc1 = (floatx4){bias_eff, bias_eff, bias_eff, bias_eff};
            floatx4 acc2 = zero4;
            #pragma unroll
            for (int kt = 0; kt < KT; ++kt) {
                bf16x8 a = *(const bf16x8*)&lds_A[rb][kt][lane][0];
                acc1 = mfma16(a, Bhi[kt], acc1);
                acc2 = mfma16(a, Blo[kt], acc2);
            }
            // fold hi/lo halves (rows r and r+8) and write next A-frag
            float s[4], pr[4];
            #pragma unroll
            for (int reg = 0; reg < 4; ++reg) {
                s[reg]  = acc1[reg] + acc2[reg];
                pr[reg] = __shfl(s[reg], lane ^ 32, 64);
            }
            if (e_wr) {
                #pragma unroll
                for (int reg = 0; reg < 4; ++reg) {
                    float v  = fast_tanh(s[reg] + pr[reg]);
                    __bf16 h = (__bf16)v;
                    // quads 0,1 write hi rows (arow 0-7); quads 2,3 write lo rows (8-15)
                    __bf16 wval = (quad < 2) ? h : (__bf16)(v - (float)h);
                    lds_A[wb][e_ktd][e_rowb + reg][e_idx] = wval;
                    if (t == T_STEPS - 1 && quad < 2) lds_h[quad*4 + reg][jcol] = v;
                }
            }
        } else if (wv == 15) {
            // stage x[t+1] into slot 7 of wb
            const int tn = (t + 1 < T_STEPS) ? (t + 1) : t;
            const float* p = xrow + (size_t)tn * tstride;
            floatx4 f0 = *(const floatx4*)p;
            floatx4 f1 = (quad < 3) ? *(const floatx4*)(p + 4) : zero4;
            float xv[8] = {f0[0],f0[1],f0[2],f0[3], f1[0],f1[1],f1[2],f1[3]};
            bf16x8 ax;
            #pragma unroll
            for (int i = 0; i < 8; ++i) {
                __bf16 h = (__bf16)xv[i];
                ax[i] = isLo ? (__bf16)(xv[i] - (float)h) : h;
            }
            *(bf16x8*)&lds_A[wb][7][lane][0] = ax;
        }
    }

    __syncthreads();

    // ---- output: out[b][o] = sum_k h[b][k]*A[o][k] + c[o] (tiny, scalar) ----
    if (tid < BB * OUT_DIM) {
        const int r = tid / OUT_DIM;
        const int o = tid % OUT_DIM;
        float s = cvec[o];
        for (int k = 0; k < HID; ++k) s += lds_h[r][k] * A[o*HID + k];
        out[(size_t)(b0 + r) * OUT_DIM + o] = s;
    }
}

extern "C" void kernel_launch(void* const* d_in, const int* in_sizes, int n_in,
                              void* d_out, int out_size, void* d_ws, size_t ws_size,
                              hipStream_t stream) {
    const float* x  = (const float*)d_in[0];
    const float* H  = (const float*)d_in[1];
    const float* U  = (const float*)d_in[2];
    const float* A  = (const float*)d_in[3];
    const float* b  = (const float*)d_in[4];
    const float* c  = (const float*)d_in[5];
    float* out = (float*)d_out;

    rnn_kernel<<<dim3(BATCH / BB), dim3(1024), 0, stream>>>(x, H, U, A, b, c, out);
}

// Round 5
// 620.971 us; speedup vs baseline: 3.5989x; 1.0048x over previous
//
#include <hip/hip_runtime.h>

// SimpleRNN: h_{t+1} = tanh(h_t @ H^T + x_t @ U + b); out = h_T @ A^T + c
// T=512 B=2048 IN=28 HID=198 OUT=10, all fp32.
//
// R5: persistent kernel, grid=256 (1 block/CU), BB=8 batch rows/block,
// 1024 threads = 16 waves = 4 waves/SIMD.
// Waves 0-12: compute (1 N-tile of 16 cols each); wave 15: x-stager.
//
// hi/lo-packed M: A rows 0-7 = h_hi, rows 8-15 = h_lo; 2 MFMA passes
// (Bhi, Blo), fold C[r]+C[r+8] -> exact (hi+lo)*(Bhi+Blo).
// R5 deltas vs R4:
//  - fold via v_permlane32_swap_b32 (VALU) instead of __shfl (ds_bpermute):
//    removes 52 LDS-pipe ops/step/CU from the bottleneck pipe.
//  - tanh = 1 - 2*rcp(exp2(2*log2e*x)+1): 5 VALU instr, saturates correctly.
// One __syncthreads per step; x@U folded as K-slot 7 with B=U.

#define T_STEPS 512
#define BATCH   2048
#define IN_DIM  28
#define HID     198
#define OUT_DIM 10
#define BB      8    // batch rows per block
#define KT      8    // 7 H k-tiles (224 >= 198) + 1 U/x slot
#define NCW     13   // compute waves / N-tiles

typedef __attribute__((ext_vector_type(8))) __bf16 bf16x8;
typedef __attribute__((ext_vector_type(4))) float  floatx4;

__device__ __forceinline__ floatx4 mfma16(bf16x8 a, bf16x8 b, floatx4 c) {
    return __builtin_amdgcn_mfma_f32_16x16x32_bf16(a, b, c, 0, 0, 0);
}

// tanh(x) = 1 - 2/(exp(2x)+1); exp2-based, saturates via IEEE inf/0.
__device__ __forceinline__ float fast_tanh(float x) {
    float e = __builtin_amdgcn_exp2f(x * 2.885390081777926357f); // exp(2x)
    float r = __builtin_amdgcn_rcpf(e + 1.0f);
    return __builtin_fmaf(-2.0f, r, 1.0f);
}

// s[lane] + s[lane^32] in every lane, without touching the LDS pipe.
__device__ __forceinline__ float fold32(float s, int lane) {
#if defined(__has_builtin) && __has_builtin(__builtin_amdgcn_permlane32_swap)
    int si = __float_as_int(s);
    auto pq = __builtin_amdgcn_permlane32_swap(si, si, false, false);
    return __int_as_float(pq[0]) + __int_as_float(pq[1]);
#else
    return s + __shfl(s, lane ^ 32, 64);
#endif
}

__global__ void __launch_bounds__(1024, 4)
rnn_kernel(const float* __restrict__ x, const float* __restrict__ H,
           const float* __restrict__ U, const float* __restrict__ A,
           const float* __restrict__ bvec, const float* __restrict__ cvec,
           float* __restrict__ out)
{
    // A-frag ping-pong: [buf][kt][lane][idx]; lane = qt*16 + arow,
    // arow 0-7 = h_hi(batch row arow), 8-15 = h_lo(batch row arow-8).
    // Slot kt=7 holds the x fragment (written by the stager wave).
    __shared__ __align__(16) __bf16 lds_A[2][KT][64][8];   // 16 KB
    __shared__ float lds_h[BB][204];                        // final h, fp32

    const int tid  = threadIdx.x;
    const int lane = tid & 63;
    const int wv   = tid >> 6;          // wave id 0..15
    const int m    = lane & 15;         // A-row / C-col index within tile
    const int quad = lane >> 4;         // 0..3
    const int b0   = blockIdx.x * BB;

    // zero-init H-slots (kt 0..6) of both buffers: h0 = 0, phantom K rows
    // stay 0 forever (epilogue never writes k >= 198).
    {
        __bf16* p0 = &lds_A[0][0][0][0];
        __bf16* p1 = &lds_A[1][0][0][0];
        for (int i = tid; i < 7*64*8; i += 1024) { p0[i] = (__bf16)0.0f; p1[i] = (__bf16)0.0f; }
    }

    const int r8    = m & 7;
    const bool isLo = (m >= 8);

    // ---- compute-wave setup: stationary B fragments + epilogue indices ----
    bf16x8 Bhi[KT], Blo[KT];
    float  bias_eff = 0.0f;
    int    jcol = 0, e_ktd = 0, e_rowb = 0, e_idx = 0;
    bool   e_wr = false;
    if (wv < NCW) {
        jcol = wv*16 + m;                               // output column (>=198 phantom)
        bias_eff = (jcol < HID && quad < 2) ? bvec[jcol] : 0.0f;
        #pragma unroll
        for (int kt = 0; kt < 7; ++kt) {
            bf16x8 hi8, lo8;
            #pragma unroll
            for (int idx = 0; idx < 8; ++idx) {
                int k = kt*32 + quad*8 + idx;
                float v = (jcol < HID && k < HID) ? H[jcol*HID + k] : 0.0f;  // B[k][j]=H[j][k]
                __bf16 h = (__bf16)v;
                hi8[idx] = h;
                lo8[idx] = (__bf16)(v - (float)h);
            }
            Bhi[kt] = hi8; Blo[kt] = lo8;
        }
        {   // slot 7: U
            bf16x8 uh, ul;
            #pragma unroll
            for (int idx = 0; idx < 8; ++idx) {
                int i = quad*8 + idx;
                float v = (jcol < HID && i < IN_DIM) ? U[i*HID + jcol] : 0.0f;
                __bf16 h = (__bf16)v;
                uh[idx] = h;
                ul[idx] = (__bf16)(v - (float)h);
            }
            Bhi[7] = uh; Blo[7] = ul;
        }
        e_ktd  = jcol >> 5;
        e_rowb = ((jcol & 31) >> 3)*16 + quad*4;  // + reg gives the A-row slot
        e_idx  = jcol & 7;
        e_wr   = (jcol < HID);
    }

    // ---- stager-wave setup: pack x[0] into slot 7 of buffer 0 ----
    const float* xrow = x + (size_t)(b0 + r8) * IN_DIM + quad*8;
    const size_t tstride = (size_t)BATCH * IN_DIM;
    floatx4 zero4 = {0.0f, 0.0f, 0.0f, 0.0f};
    if (wv == 15) {
        floatx4 f0 = *(const floatx4*)xrow;
        floatx4 f1 = (quad < 3) ? *(const floatx4*)(xrow + 4) : zero4;
        float xv[8] = {f0[0],f0[1],f0[2],f0[3], f1[0],f1[1],f1[2],f1[3]};
        bf16x8 ax;
        #pragma unroll
        for (int i = 0; i < 8; ++i) {
            __bf16 h = (__bf16)xv[i];
            ax[i] = isLo ? (__bf16)(xv[i] - (float)h) : h;
        }
        *(bf16x8*)&lds_A[0][7][lane][0] = ax;
    }

    // ================= time loop =================
    #pragma unroll 1
    for (int t = 0; t < T_STEPS; ++t) {
        const int rb = t & 1;
        const int wb = rb ^ 1;

        __syncthreads();   // all prior writes into rb visible; wb free to write

        if (wv < NCW) {
            floatx4 acc1 = (floatx4){bias_eff, bias_eff, bias_eff, bias_eff};
            floatx4 acc2 = zero4;
            #pragma unroll
            for (int kt = 0; kt < KT; ++kt) {
                bf16x8 a = *(const bf16x8*)&lds_A[rb][kt][lane][0];
                acc1 = mfma16(a, Bhi[kt], acc1);
                acc2 = mfma16(a, Blo[kt], acc2);
            }
            // fold hi/lo halves (C rows r and r+8) in-register, then tanh+write
            if (e_wr) {
                #pragma unroll
                for (int reg = 0; reg < 4; ++reg) {
                    float v  = fast_tanh(fold32(acc1[reg] + acc2[reg], lane));
                    __bf16 h = (__bf16)v;
                    // quads 0,1 write hi rows (arow 0-7); quads 2,3 write lo rows (8-15)
                    __bf16 wval = (quad < 2) ? h : (__bf16)(v - (float)h);
                    lds_A[wb][e_ktd][e_rowb + reg][e_idx] = wval;
                    if (t == T_STEPS - 1 && quad < 2) lds_h[quad*4 + reg][jcol] = v;
                }
            } else {
                // keep all lanes converged through the permlane fold region
                #pragma unroll
                for (int reg = 0; reg < 4; ++reg) (void)fold32(acc1[reg] + acc2[reg], lane);
            }
        } else if (wv == 15) {
            // stage x[t+1] into slot 7 of wb
            const int tn = (t + 1 < T_STEPS) ? (t + 1) : t;
            const float* p = xrow + (size_t)tn * tstride;
            floatx4 f0 = *(const floatx4*)p;
            floatx4 f1 = (quad < 3) ? *(const floatx4*)(p + 4) : zero4;
            float xv[8] = {f0[0],f0[1],f0[2],f0[3], f1[0],f1[1],f1[2],f1[3]};
            bf16x8 ax;
            #pragma unroll
            for (int i = 0; i < 8; ++i) {
                __bf16 h = (__bf16)xv[i];
                ax[i] = isLo ? (__bf16)(xv[i] - (float)h) : h;
            }
            *(bf16x8*)&lds_A[wb][7][lane][0] = ax;
        }
    }

    __syncthreads();

    // ---- output: out[b][o] = sum_k h[b][k]*A[o][k] + c[o] (tiny, scalar) ----
    if (tid < BB * OUT_DIM) {
        const int r = tid / OUT_DIM;
        const int o = tid % OUT_DIM;
        float s = cvec[o];
        for (int k = 0; k < HID; ++k) s += lds_h[r][k] * A[o*HID + k];
        out[(size_t)(b0 + r) * OUT_DIM + o] = s;
    }
}

extern "C" void kernel_launch(void* const* d_in, const int* in_sizes, int n_in,
                              void* d_out, int out_size, void* d_ws, size_t ws_size,
                              hipStream_t stream) {
    const float* x  = (const float*)d_in[0];
    const float* H  = (const float*)d_in[1];
    const float* U  = (const float*)d_in[2];
    const float* A  = (const float*)d_in[3];
    const float* b  = (const float*)d_in[4];
    const float* c  = (const float*)d_in[5];
    float* out = (float*)d_out;

    rnn_kernel<<<dim3(BATCH / BB), dim3(1024), 0, stream>>>(x, H, U, A, b, c, out);
}